// Round 15
// baseline (169.415 us; speedup 1.0000x reference)
//
#include <hip/hip_runtime.h>
#include <math.h>

// QCCNN fused kernel for MI355X (gfx950) — Round 15 (= R14 resubmit; R14 hit a
// GPU-acquisition timeout and never ran).
// R13 post-mortem: FAILED correctness (absmax 0.12) — s_feats was declared
// [64][28] but indexed with full per-image feature offsets (k*27+pt+{0,9,18},
// max 107; phase-B reads up to 104): neighboring images' rows overlapped.
// Fix: s_feats[64][112] (448B row stride: 16B-aligned for float4, 112%32=16 ->
// only 2-way bank aliasing, free). Everything else identical to R13:
//   Phase A: thread (img,k) — M[4][8] hoisted to 32 REGISTERS, normalization
//     folded into a final inv2 feature scale (features are quadratic in amps),
//     gate-3 applied directly to the loaded float2 pairs. Quantum loop = pure
//     VALU + 8 L1-hot loads/patch, ZERO in-loop LDS reads.
//   Phase B: thread (img,k) owns o in {k,4+k,...,28+k}; fc1 from LDS float4,
//     fc2 partials shfl_xor-reduced over the 4 k-lanes, lane k=0 writes.

#define QC_EPS 1e-12f

__device__ __forceinline__ float leakyf(float v) { return v >= 0.0f ? v : 0.1f * v; }

__global__ __launch_bounds__(256) void qccnn_fused(
    const float* __restrict__ x,     // (B,1,8,8)
    const float* __restrict__ qw,    // (4,4,3)
    const float* __restrict__ w1,    // (32,108)
    const float* __restrict__ b1,    // (32,)
    const float* __restrict__ w2,    // (3,32)
    const float* __restrict__ b2,    // (3,)
    float* __restrict__ out,         // (B,3)
    int Bsz)
{
    __shared__ float s_w1[32][116];  // 14.8 KB row-major [o][f]; stride 464B (16B-aligned)
    __shared__ float s_feats[64][112]; // 28.7 KB; 108 feats/image + pad; stride 448B
    __shared__ float s_qm[4][4][9];  // 0.6 KB; read once into registers after barrier

    const int tid = threadIdx.x;

    // ---- stage w1 row-major: s_w1[o][f] = w1[o*108+f] ----
    for (int idx = tid; idx < 32 * 108; idx += 256) {
        const int o = idx / 108, f = idx % 108;
        s_w1[o][f] = w1[idx];
    }
    // ---- rotation matrices ----
    if (tid < 16) {
        const int k = tid >> 2, q = tid & 3;
        const float phi = qw[(k * 4 + q) * 3 + 0];
        const float th  = qw[(k * 4 + q) * 3 + 1];
        const float om  = qw[(k * 4 + q) * 3 + 2];
        float c, s, ca, sa, cb, sb;
        sincosf(0.5f * th, &s, &c);
        sincosf(0.5f * (phi + om), &sa, &ca);
        sincosf(0.5f * (phi - om), &sb, &cb);
        float* M = &s_qm[k][q][0];
        // m00 = exp(-i(phi+om)/2)*c ; m01 = -exp(+i(phi-om)/2)*s
        // m10 = exp(-i(phi-om)/2)*s ; m11 = exp(+i(phi+om)/2)*c
        M[0] =  ca * c;  M[1] = -sa * c;
        M[2] = -cb * s;  M[3] = -sb * s;
        M[4] =  cb * s;  M[5] = -sb * s;
        M[6] =  ca * c;  M[7] =  sa * c;
    }
    __syncthreads();

    const int img_l = tid >> 2;          // 0..63
    const int k     = tid & 3;           // this thread's quantum kernel
    const int b     = blockIdx.x * 64 + img_l;
    const bool valid = (b < Bsz);
    const float* xb = x + (size_t)b * 64;

    // ---- M hoisted into registers for the whole kernel (static indices) ----
    float M[4][8];
#pragma unroll
    for (int q = 0; q < 4; ++q)
#pragma unroll
        for (int e = 0; e < 8; ++e) M[q][e] = s_qm[k][q][e];

    // CNOT chain (0,1)(1,2)(2,3)(3,0) folded into measurement indexing
    constexpr int PERM[16] = {0, 13, 3, 14, 6, 11, 5, 8, 12, 1, 15, 2, 10, 7, 9, 4};

    // =====================  PHASE A: quantum features  =====================
    int pi = 0, pj = 0;
#pragma unroll 1
    for (int pt = 0; pt < 9; ++pt) {
        // ---- load patch rows; gate on qubit 3 applied DIRECTLY (no p array,
        //      no pre-normalization: features scaled by inv2 at the end) ----
        float sr[16], si[16];
        float ss = 0.0f;
        if (valid) {
            const float* pr = xb + pi * 16 + pj * 2;
            const float m00r = M[3][0], m00i = M[3][1], m01r = M[3][2], m01i = M[3][3];
            const float m10r = M[3][4], m10i = M[3][5], m11r = M[3][6], m11i = M[3][7];
#pragma unroll
            for (int r = 0; r < 4; ++r) {
                const float2 lo = *reinterpret_cast<const float2*>(pr + r * 8);
                const float2 hi = *reinterpret_cast<const float2*>(pr + r * 8 + 2);
                ss += lo.x * lo.x + lo.y * lo.y + hi.x * hi.x + hi.y * hi.y;
                sr[4 * r + 0] = m00r * lo.x + m01r * lo.y;
                si[4 * r + 0] = m00i * lo.x + m01i * lo.y;
                sr[4 * r + 1] = m10r * lo.x + m11r * lo.y;
                si[4 * r + 1] = m10i * lo.x + m11i * lo.y;
                sr[4 * r + 2] = m00r * hi.x + m01r * hi.y;
                si[4 * r + 2] = m00i * hi.x + m01i * hi.y;
                sr[4 * r + 3] = m10r * hi.x + m11r * hi.y;
                si[4 * r + 3] = m10i * hi.x + m11i * hi.y;
            }
        } else {
#pragma unroll
            for (int l = 0; l < 16; ++l) { sr[l] = 0.0f; si[l] = 0.0f; }
        }

        // ---- gates on qubits 2,1,0 (masks 2,4,8), M from registers ----
#pragma unroll
        for (int g = 0; g < 3; ++g) {
            const int qq = (g == 0) ? 2 : ((g == 1) ? 1 : 0);
            const int m  = (g == 0) ? 2 : ((g == 1) ? 4 : 8);
            const float m00r = M[qq][0], m00i = M[qq][1], m01r = M[qq][2], m01i = M[qq][3];
            const float m10r = M[qq][4], m10i = M[qq][5], m11r = M[qq][6], m11i = M[qq][7];
#pragma unroll
            for (int i0 = 0; i0 < 16; ++i0) {
                if (i0 & m) continue;
                const int i1 = i0 | m;
                const float t0r = sr[i0], t0i = si[i0];
                const float t1r = sr[i1], t1i = si[i1];
                sr[i0] = m00r * t0r - m00i * t0i + m01r * t1r - m01i * t1i;
                si[i0] = m00r * t0i + m00i * t0r + m01r * t1i + m01i * t1r;
                sr[i1] = m10r * t0r - m10i * t0i + m11r * t1r - m11i * t1i;
                si[i1] = m10r * t0i + m10i * t0r + m11r * t1i + m11i * t1r;
            }
        }

        // ---- measurement (CNOT perm folded in) ----
        float abr = 0.0f, abi = 0.0f, zz = 0.0f;
#pragma unroll
        for (int jj = 0; jj < 8; ++jj) {
            const int ia = PERM[jj], ib = PERM[8 + jj];
            const float ar = sr[ia], ai = si[ia];
            const float br = sr[ib], bi = si[ib];
            abr += ar * br + ai * bi;
            abi += ar * bi - ai * br;
            zz  += (ar * ar + ai * ai) - (br * br + bi * bi);
        }

        // ---- deferred normalization + leaky -> LDS ----
        {
            const float denom = sqrtf(ss) + QC_EPS;
            const float inv2  = 1.0f / (denom * denom);   // amps = p/denom, feats quadratic
            const float f0 = leakyf(2.0f * abr * inv2);
            const float f1 = leakyf(2.0f * abi * inv2);
            const float f2 = leakyf(zz * inv2);
            float* row = &s_feats[img_l][k * 27 + pt];
            row[0]  = f0;
            row[9]  = f1;
            row[18] = f2;
        }

        if (++pj == 3) { pj = 0; ++pi; }
    }
    __syncthreads();

    // =====================  PHASE B: fc1 + fc2  =====================
    // thread (img,k) owns outputs o = 4*j + k, j = 0..7
    float h[8];
#pragma unroll
    for (int j = 0; j < 8; ++j) h[j] = 0.0f;

#pragma unroll 1
    for (int f4 = 0; f4 < 27; ++f4) {
        const float4 fv = *reinterpret_cast<const float4*>(&s_feats[img_l][f4 * 4]);
#pragma unroll
        for (int j = 0; j < 8; ++j) {
            const float4 wv = *reinterpret_cast<const float4*>(&s_w1[4 * j + k][f4 * 4]);
            h[j] += wv.x * fv.x + wv.y * fv.y + wv.z * fv.z + wv.w * fv.w;
        }
    }

    float o0 = 0.0f, o1 = 0.0f, o2 = 0.0f;
#pragma unroll
    for (int j = 0; j < 8; ++j) {
        const int o = 4 * j + k;
        const float hv = leakyf(h[j] + b1[o]);
        o0 += w2[o] * hv;
        o1 += w2[32 + o] * hv;
        o2 += w2[64 + o] * hv;
    }
    // reduce the 3 fc2 partials across the 4 k-lanes (contiguous lanes of a wave)
    o0 += __shfl_xor(o0, 1);  o0 += __shfl_xor(o0, 2);
    o1 += __shfl_xor(o1, 1);  o1 += __shfl_xor(o1, 2);
    o2 += __shfl_xor(o2, 1);  o2 += __shfl_xor(o2, 2);

    if (k == 0 && valid) {
        float* ob = out + (size_t)b * 3;
        ob[0] = o0 + b2[0];
        ob[1] = o1 + b2[1];
        ob[2] = o2 + b2[2];
    }
}

extern "C" void kernel_launch(void* const* d_in, const int* in_sizes, int n_in,
                              void* d_out, int out_size, void* d_ws, size_t ws_size,
                              hipStream_t stream) {
    (void)n_in; (void)out_size; (void)d_ws; (void)ws_size;
    const float* x  = (const float*)d_in[0];
    const float* qw = (const float*)d_in[1];
    const float* w1 = (const float*)d_in[2];
    const float* b1 = (const float*)d_in[3];
    const float* w2 = (const float*)d_in[4];
    const float* b2 = (const float*)d_in[5];
    float* out = (float*)d_out;

    const int Bsz = in_sizes[0] / 64;            // x is (B,1,8,8)
    const int blocks = (Bsz + 63) / 64;          // 64 images per block

    qccnn_fused<<<blocks, 256, 0, stream>>>(x, qw, w1, b1, w2, b2, out, Bsz);
}